// Round 7
// baseline (506.511 us; speedup 1.0000x reference)
//
#include <hip/hip_runtime.h>
#include <hip/hip_bf16.h>
#include <stdint.h>

typedef int i32x4 __attribute__((ext_vector_type(4)));

#define QMAX 127.0f

// ---------------- init: zero the two absmax slots (ws is poisoned 0xAA) ----
__global__ void k_init(unsigned* slots) {
  if (threadIdx.x < 2) slots[threadIdx.x] = 0u;
}

// ---------------- per-tensor absmax (fp32, float4 loads) -------------------
__global__ void k_absmax(const float4* __restrict__ x, int n4,
                         unsigned* __restrict__ slot) {
  float m = 0.f;
  int stride = gridDim.x * blockDim.x;
  for (int i = blockIdx.x * blockDim.x + threadIdx.x; i < n4; i += stride) {
    float4 v = x[i];
    m = fmaxf(m, fmaxf(fmaxf(fabsf(v.x), fabsf(v.y)),
                       fmaxf(fabsf(v.z), fabsf(v.w))));
  }
#pragma unroll
  for (int off = 32; off > 0; off >>= 1)
    m = fmaxf(m, __shfl_xor(m, off, 64));
  __shared__ float wmax[4];
  if ((threadIdx.x & 63) == 0) wmax[threadIdx.x >> 6] = m;
  __syncthreads();
  if (threadIdx.x == 0) {
    float mm = fmaxf(fmaxf(wmax[0], wmax[1]), fmaxf(wmax[2], wmax[3]));
    // non-negative floats order like their uint bit patterns
    atomicMax(slot, __float_as_uint(mm));
  }
}

// ---------------- quantize fp32 -> packed int8 -----------------------------
// q = clip(rint(x/scale), -128, 127), scale = absmax/127 (0 -> 1).
// rintf = round-half-even = jnp.round; x/scale is IEEE-exact same as ref.
// q fits int8 exactly; 4 int8 packed per 32-bit store.
__global__ void k_quantize(const float4* __restrict__ x, unsigned* __restrict__ q,
                           int n4, const unsigned* __restrict__ amax_bits) {
  float amax = __uint_as_float(*amax_bits);
  float scale = amax / QMAX;
  if (scale == 0.f) scale = 1.f;
  int stride = gridDim.x * blockDim.x;
  for (int i = blockIdx.x * blockDim.x + threadIdx.x; i < n4; i += stride) {
    float4 v = x[i];
    // integral floats in [-128,127]; (int) cast exact
    int q0 = (int)fminf(fmaxf(rintf(v.x / scale), -128.f), 127.f);
    int q1 = (int)fminf(fmaxf(rintf(v.y / scale), -128.f), 127.f);
    int q2 = (int)fminf(fmaxf(rintf(v.z / scale), -128.f), 127.f);
    int q3 = (int)fminf(fmaxf(rintf(v.w / scale), -128.f), 127.f);
    q[i] = (unsigned)(q0 & 255) | ((unsigned)(q1 & 255) << 8) |
           ((unsigned)(q2 & 255) << 16) | ((unsigned)(q3 & 255) << 24);
  }
}

// ---------------- int8 GEMM, B^T layout (m97 structure, byte-identical) ----
// C[m][n] = s * sum_k A[m][k]*B[n][k] + bias[n], A/B int8, acc int32 (exact).
// 128x128 tile, BK=64 i8 (64 B/row — same bytes as BK=32 bf16), 4 waves,
// 16x16x64 i8 MFMA, global_load_lds width=16, linear LDS, XCD swizzle.
#define BM 128
#define BN 128
#define BK 64

__global__ __launch_bounds__(256) void k_gemm(
    const signed char* __restrict__ Aq, const signed char* __restrict__ Bq,
    const float* __restrict__ bias, const unsigned* __restrict__ slots,
    float* __restrict__ C, int M, int N, int K)
{
  __shared__ alignas(16) signed char As[BM][BK];   // 8 KB
  __shared__ alignas(16) signed char Bs[BN][BK];   // 8 KB

  const int tid  = threadIdx.x;
  const int lane = tid & 63;
  const int wave = tid >> 6;
  const int wm = wave >> 1, wn = wave & 1;

  const int nbx = N / BN;
  const int nwg = gridDim.x;
  int bx = blockIdx.x;
  if ((nwg & 7) == 0) {                 // bijective XCD swizzle (nwg%8==0)
    int cpx = nwg >> 3;
    bx = (bx & 7) * cpx + (bx >> 3);
  }
  const int brow = (bx / nbx) * BM;
  const int bcol = (bx % nbx) * BN;

  const int lrow = lane & 15;           // fragment row (A) / col (B)
  const int lkob = (lane >> 4) * 16;    // k-byte-offset of this lane-group

  const signed char* Ag = Aq + (size_t)brow * K;
  const signed char* Bg = Bq + (size_t)bcol * K;

  i32x4 acc[4][4] = {};                 // int32 accum, bit-exact

  for (int k0 = 0; k0 < K; k0 += BK) {
    // stage A,B tiles: 8 KB each = 2 wave-issues x 4 waves x 16B/lane
#pragma unroll
    for (int c = 0; c < 2; ++c) {
      int lin = c * 256 + tid;          // 16B units; 4 per 64B row
      int row = lin >> 2, unit = lin & 3;
      __builtin_amdgcn_global_load_lds(
          (__attribute__((address_space(1))) void*)(Ag + (size_t)row * K + k0 + unit * 16),
          (__attribute__((address_space(3))) void*)((signed char*)&As[0][0] + lin * 16),
          16, 0, 0);
    }
#pragma unroll
    for (int c = 0; c < 2; ++c) {
      int lin = c * 256 + tid;
      int row = lin >> 2, unit = lin & 3;
      __builtin_amdgcn_global_load_lds(
          (__attribute__((address_space(1))) void*)(Bg + (size_t)row * K + k0 + unit * 16),
          (__attribute__((address_space(3))) void*)((signed char*)&Bs[0][0] + lin * 16),
          16, 0, 0);
    }
    __syncthreads();   // compiler drains vmcnt before s_barrier

    i32x4 af[4], bfr[4];
#pragma unroll
    for (int mi = 0; mi < 4; ++mi)
      af[mi] = *(const i32x4*)&As[wm * 64 + mi * 16 + lrow][lkob];
#pragma unroll
    for (int ni = 0; ni < 4; ++ni)
      bfr[ni] = *(const i32x4*)&Bs[wn * 64 + ni * 16 + lrow][lkob];
#pragma unroll
    for (int mi = 0; mi < 4; ++mi)
#pragma unroll
      for (int ni = 0; ni < 4; ++ni)
        acc[mi][ni] = __builtin_amdgcn_mfma_i32_16x16x64_i8(
            af[mi], bfr[ni], acc[mi][ni], 0, 0, 0);

    __syncthreads();
  }

  // epilogue: dequant scale + bias. |dot| <= 128*128*4096 < 2^31 (no ovf).
  float sx = __uint_as_float(slots[0]) / QMAX; if (sx == 0.f) sx = 1.f;
  float sw = __uint_as_float(slots[1]) / QMAX; if (sw == 0.f) sw = 1.f;
  const float s = sx * sw;

  // C/D layout dtype-independent (m121-m128): col=lane&15, row=(lane>>4)*4+reg
#pragma unroll
  for (int mi = 0; mi < 4; ++mi)
#pragma unroll
    for (int ni = 0; ni < 4; ++ni) {
      const int n = bcol + wn * 64 + ni * 16 + lrow;
      const float b = bias[n];
#pragma unroll
      for (int r = 0; r < 4; ++r) {
        const int m = brow + wm * 64 + mi * 16 + (lane >> 4) * 4 + r;
        C[(size_t)m * N + n] = (float)acc[mi][ni][r] * s + b;
      }
    }
}

extern "C" void kernel_launch(void* const* d_in, const int* in_sizes, int n_in,
                              void* d_out, int out_size, void* d_ws, size_t ws_size,
                              hipStream_t stream) {
  const float* x    = (const float*)d_in[0];   // [M][K] fp32
  const float* w    = (const float*)d_in[1];   // [N][K] fp32
  const float* bias = (const float*)d_in[2];   // [N]    fp32
  float* out = (float*)d_out;                  // [M][N] fp32

  const int O = in_sizes[2];                   // 4096 out_features
  const int K = in_sizes[1] / O;               // 4096 in_features
  const int M = in_sizes[0] / K;               // 8192 tokens

  // workspace layout: [0..7] absmax slots, 256B-aligned qx (i8), then qw (i8)
  unsigned* slots = (unsigned*)d_ws;
  signed char* qx = (signed char*)d_ws + 256;
  signed char* qw = qx + (size_t)M * K;
  // needs 256 + M*K + O*K bytes ≈ 50.3 MB of ws

  k_init<<<1, 64, 0, stream>>>(slots);
  k_absmax<<<2048, 256, 0, stream>>>((const float4*)x, M * K / 4, slots + 0);
  k_absmax<<<1024, 256, 0, stream>>>((const float4*)w, O * K / 4, slots + 1);
  k_quantize<<<2048, 256, 0, stream>>>((const float4*)x, (unsigned*)qx, M * K / 4, slots + 0);
  k_quantize<<<2048, 256, 0, stream>>>((const float4*)w, (unsigned*)qw, O * K / 4, slots + 1);

  const int grid = (M / BM) * (O / BN);        // 64 * 32 = 2048
  k_gemm<<<grid, 256, 0, stream>>>(qx, qw, bias, slots, out, M, O, K);
}

// Round 9
// 473.944 us; speedup vs baseline: 1.0687x; 1.0687x over previous
//
#include <hip/hip_runtime.h>
#include <hip/hip_bf16.h>
#include <stdint.h>

typedef int i32x4 __attribute__((ext_vector_type(4)));

#define QMAX 127.0f

// ---------------- init: zero the two absmax slots (ws is poisoned 0xAA) ----
__global__ void k_init(unsigned* slots) {
  if (threadIdx.x < 2) slots[threadIdx.x] = 0u;
}

// ---------------- fused per-tensor absmax for BOTH tensors -----------------
// blocks [0,BX) -> tensor x (slot 0), [BX,grid) -> tensor w (slot 1).
// 4 independent accumulators / 4 outstanding float4 loads per outer iter.
__global__ __launch_bounds__(256) void k_absmax2(
    const float4* __restrict__ x, int n4x,
    const float4* __restrict__ w, int n4w,
    int BX, int BW, unsigned* __restrict__ slots) {
  const int b = blockIdx.x;
  const float4* src; int n4, rtid, rthreads; unsigned* slot;
  if (b < BX) { src = x; n4 = n4x; rtid = b * 256 + threadIdx.x;
                rthreads = BX * 256; slot = slots + 0; }
  else        { src = w; n4 = n4w; rtid = (b - BX) * 256 + threadIdx.x;
                rthreads = BW * 256; slot = slots + 1; }

  float m0 = 0.f, m1 = 0.f, m2 = 0.f, m3 = 0.f;
  int i = rtid;
  for (; i + 3 * rthreads < n4; i += 4 * rthreads) {
    float4 v0 = src[i];
    float4 v1 = src[i + rthreads];
    float4 v2 = src[i + 2 * rthreads];
    float4 v3 = src[i + 3 * rthreads];
    m0 = fmaxf(m0, fmaxf(fmaxf(fabsf(v0.x), fabsf(v0.y)), fmaxf(fabsf(v0.z), fabsf(v0.w))));
    m1 = fmaxf(m1, fmaxf(fmaxf(fabsf(v1.x), fabsf(v1.y)), fmaxf(fabsf(v1.z), fabsf(v1.w))));
    m2 = fmaxf(m2, fmaxf(fmaxf(fabsf(v2.x), fabsf(v2.y)), fmaxf(fabsf(v2.z), fabsf(v2.w))));
    m3 = fmaxf(m3, fmaxf(fmaxf(fabsf(v3.x), fabsf(v3.y)), fmaxf(fabsf(v3.z), fabsf(v3.w))));
  }
  for (; i < n4; i += rthreads) {
    float4 v = src[i];
    m0 = fmaxf(m0, fmaxf(fmaxf(fabsf(v.x), fabsf(v.y)), fmaxf(fabsf(v.z), fabsf(v.w))));
  }
  float m = fmaxf(fmaxf(m0, m1), fmaxf(m2, m3));
#pragma unroll
  for (int off = 32; off > 0; off >>= 1)
    m = fmaxf(m, __shfl_xor(m, off, 64));
  __shared__ float wmax[4];
  if ((threadIdx.x & 63) == 0) wmax[threadIdx.x >> 6] = m;
  __syncthreads();
  if (threadIdx.x == 0) {
    float mm = fmaxf(fmaxf(wmax[0], wmax[1]), fmaxf(wmax[2], wmax[3]));
    atomicMax(slot, __float_as_uint(mm));   // non-neg floats order as uints
  }
}

// ---------------- fused quantize for BOTH tensors --------------------------
// q = clip(rint(x/scale), -128, 127), scale = absmax/127 (0 -> 1).
// rintf = round-half-even = jnp.round; bit-identical to reference.
__global__ __launch_bounds__(256) void k_quant2(
    const float4* __restrict__ x, unsigned* __restrict__ qx, int n4x,
    const float4* __restrict__ w, unsigned* __restrict__ qw, int n4w,
    int BX, int BW, const unsigned* __restrict__ slots) {
  const int b = blockIdx.x;
  const float4* src; unsigned* dst; int n4, rtid, rthreads; unsigned abits;
  if (b < BX) { src = x; dst = qx; n4 = n4x; rtid = b * 256 + threadIdx.x;
                rthreads = BX * 256; abits = slots[0]; }
  else        { src = w; dst = qw; n4 = n4w; rtid = (b - BX) * 256 + threadIdx.x;
                rthreads = BW * 256; abits = slots[1]; }
  float scale = __uint_as_float(abits) / QMAX;
  if (scale == 0.f) scale = 1.f;

  int i = rtid;
  for (; i + 3 * rthreads < n4; i += 4 * rthreads) {
#pragma unroll
    for (int j = 0; j < 4; ++j) {
      float4 v = src[i + j * rthreads];
      int q0 = (int)fminf(fmaxf(rintf(v.x / scale), -128.f), 127.f);
      int q1 = (int)fminf(fmaxf(rintf(v.y / scale), -128.f), 127.f);
      int q2 = (int)fminf(fmaxf(rintf(v.z / scale), -128.f), 127.f);
      int q3 = (int)fminf(fmaxf(rintf(v.w / scale), -128.f), 127.f);
      dst[i + j * rthreads] = (unsigned)(q0 & 255) | ((unsigned)(q1 & 255) << 8) |
                              ((unsigned)(q2 & 255) << 16) | ((unsigned)(q3 & 255) << 24);
    }
  }
  for (; i < n4; i += rthreads) {
    float4 v = src[i];
    int q0 = (int)fminf(fmaxf(rintf(v.x / scale), -128.f), 127.f);
    int q1 = (int)fminf(fmaxf(rintf(v.y / scale), -128.f), 127.f);
    int q2 = (int)fminf(fmaxf(rintf(v.z / scale), -128.f), 127.f);
    int q3 = (int)fminf(fmaxf(rintf(v.w / scale), -128.f), 127.f);
    dst[i] = (unsigned)(q0 & 255) | ((unsigned)(q1 & 255) << 8) |
             ((unsigned)(q2 & 255) << 16) | ((unsigned)(q3 & 255) << 24);
  }
}

// ---------------- int8 GEMM, B^T layout (m97 structure, VERIFIED r7) -------
// C[m][n] = s * sum_k A[m][k]*B[n][k] + bias[n], A/B int8, acc int32 (exact).
// 128x128 tile, BK=64 i8, 4 waves, 16x16x64 i8 MFMA, global_load_lds w=16,
// linear LDS, XCD swizzle. Only r8 change: nontemporal C stores (C is
// never re-read; stop it evicting A/B panels from L2/L3 -> FETCH drop).
#define BM 128
#define BN 128
#define BK 64

__global__ __launch_bounds__(256) void k_gemm(
    const signed char* __restrict__ Aq, const signed char* __restrict__ Bq,
    const float* __restrict__ bias, const unsigned* __restrict__ slots,
    float* __restrict__ C, int M, int N, int K)
{
  __shared__ alignas(16) signed char As[BM][BK];   // 8 KB
  __shared__ alignas(16) signed char Bs[BN][BK];   // 8 KB

  const int tid  = threadIdx.x;
  const int lane = tid & 63;
  const int wave = tid >> 6;
  const int wm = wave >> 1, wn = wave & 1;

  const int nbx = N / BN;
  const int nwg = gridDim.x;
  int bx = blockIdx.x;
  if ((nwg & 7) == 0) {                 // bijective XCD swizzle (nwg%8==0)
    int cpx = nwg >> 3;
    bx = (bx & 7) * cpx + (bx >> 3);
  }
  const int brow = (bx / nbx) * BM;
  const int bcol = (bx % nbx) * BN;

  const int lrow = lane & 15;           // fragment row (A) / col (B)
  const int lkob = (lane >> 4) * 16;    // k-byte-offset of this lane-group

  const signed char* Ag = Aq + (size_t)brow * K;
  const signed char* Bg = Bq + (size_t)bcol * K;

  i32x4 acc[4][4] = {};                 // int32 accum, bit-exact

  for (int k0 = 0; k0 < K; k0 += BK) {
#pragma unroll
    for (int c = 0; c < 2; ++c) {
      int lin = c * 256 + tid;          // 16B units; 4 per 64B row
      int row = lin >> 2, unit = lin & 3;
      __builtin_amdgcn_global_load_lds(
          (__attribute__((address_space(1))) void*)(Ag + (size_t)row * K + k0 + unit * 16),
          (__attribute__((address_space(3))) void*)((signed char*)&As[0][0] + lin * 16),
          16, 0, 0);
    }
#pragma unroll
    for (int c = 0; c < 2; ++c) {
      int lin = c * 256 + tid;
      int row = lin >> 2, unit = lin & 3;
      __builtin_amdgcn_global_load_lds(
          (__attribute__((address_space(1))) void*)(Bg + (size_t)row * K + k0 + unit * 16),
          (__attribute__((address_space(3))) void*)((signed char*)&Bs[0][0] + lin * 16),
          16, 0, 0);
    }
    __syncthreads();   // compiler drains vmcnt before s_barrier

    i32x4 af[4], bfr[4];
#pragma unroll
    for (int mi = 0; mi < 4; ++mi)
      af[mi] = *(const i32x4*)&As[wm * 64 + mi * 16 + lrow][lkob];
#pragma unroll
    for (int ni = 0; ni < 4; ++ni)
      bfr[ni] = *(const i32x4*)&Bs[wn * 64 + ni * 16 + lrow][lkob];
#pragma unroll
    for (int mi = 0; mi < 4; ++mi)
#pragma unroll
      for (int ni = 0; ni < 4; ++ni)
        acc[mi][ni] = __builtin_amdgcn_mfma_i32_16x16x64_i8(
            af[mi], bfr[ni], acc[mi][ni], 0, 0, 0);

    __syncthreads();
  }

  // epilogue: dequant scale + bias. |dot| <= 128*128*4096 < 2^31 (no ovf).
  float sx = __uint_as_float(slots[0]) / QMAX; if (sx == 0.f) sx = 1.f;
  float sw = __uint_as_float(slots[1]) / QMAX; if (sw == 0.f) sw = 1.f;
  const float s = sx * sw;

  // C/D layout dtype-independent (m121-m128): col=lane&15, row=(lane>>4)*4+reg
#pragma unroll
  for (int mi = 0; mi < 4; ++mi)
#pragma unroll
    for (int ni = 0; ni < 4; ++ni) {
      const int n = bcol + wn * 64 + ni * 16 + lrow;
      const float b = bias[n];
#pragma unroll
      for (int r = 0; r < 4; ++r) {
        const int m = brow + wm * 64 + mi * 16 + (lane >> 4) * 4 + r;
        __builtin_nontemporal_store(acc[mi][ni][r] * s + b, &C[(size_t)m * N + n]);
      }
    }
}

extern "C" void kernel_launch(void* const* d_in, const int* in_sizes, int n_in,
                              void* d_out, int out_size, void* d_ws, size_t ws_size,
                              hipStream_t stream) {
  const float* x    = (const float*)d_in[0];   // [M][K] fp32
  const float* w    = (const float*)d_in[1];   // [N][K] fp32
  const float* bias = (const float*)d_in[2];   // [N]    fp32
  float* out = (float*)d_out;                  // [M][N] fp32

  const int O = in_sizes[2];                   // 4096 out_features
  const int K = in_sizes[1] / O;               // 4096 in_features
  const int M = in_sizes[0] / K;               // 8192 tokens

  // workspace layout: [0..7] absmax slots, 256B-aligned qx (i8), then qw (i8)
  unsigned* slots = (unsigned*)d_ws;
  signed char* qx = (signed char*)d_ws + 256;
  signed char* qw = qx + (size_t)M * K;
  // needs 256 + M*K + O*K bytes ≈ 50.3 MB of ws

  const int n4x = M * K / 4, n4w = O * K / 4;
  const int BX = 2048, BW = 1024;              // block split x : w (2:1 data)

  k_init<<<1, 64, 0, stream>>>(slots);
  k_absmax2<<<BX + BW, 256, 0, stream>>>((const float4*)x, n4x,
                                         (const float4*)w, n4w, BX, BW, slots);
  k_quant2<<<BX + BW, 256, 0, stream>>>((const float4*)x, (unsigned*)qx, n4x,
                                        (const float4*)w, (unsigned*)qw, n4w,
                                        BX, BW, slots);

  const int grid = (M / BM) * (O / BN);        // 64 * 32 = 2048
  k_gemm<<<grid, 256, 0, stream>>>(qx, qw, bias, slots, out, M, O, K);
}